// Round 11
// baseline (125.425 us; speedup 1.0000x reference)
//
#include <hip/hip_runtime.h>
#include <hip/hip_bf16.h>

using floatx4 = __attribute__((ext_vector_type(4))) float;
using int4v   = __attribute__((ext_vector_type(4))) int;
using int8v   = __attribute__((ext_vector_type(8))) int;

#define TEMP_INV 14.285714285714286f  // 1/0.07
#define DD 256   // feature dim; one fp8 row = 256 B
#define BM 128
#define NCT 4    // column tiles per block
#define SC1 127  // e8m0 exponent 127 -> scale 1.0

// ---- kernel 1: L2 normalize rows -> fp8 e4m3, plus exact fp8 diag dot ----
__global__ __launch_bounds__(256) void nrm_kernel(
    const float* __restrict__ anchor, const float* __restrict__ positive,
    unsigned char* __restrict__ a8, unsigned char* __restrict__ p8,
    float* __restrict__ diag) {
  const int wave = threadIdx.x >> 6;
  const int lane = threadIdx.x & 63;
  const int row  = blockIdx.x * 4 + wave;
  const float4 va = ((const float4*)(anchor   + (size_t)row * DD))[lane];
  const float4 vp = ((const float4*)(positive + (size_t)row * DD))[lane];
  float sa = va.x * va.x + va.y * va.y + va.z * va.z + va.w * va.w;
  float sp = vp.x * vp.x + vp.y * vp.y + vp.z * vp.z + vp.w * vp.w;
#pragma unroll
  for (int m = 32; m >= 1; m >>= 1) {
    sa += __shfl_xor(sa, m, 64);
    sp += __shfl_xor(sp, m, 64);
  }
  const float ka = 1.0f / fmaxf(sqrtf(sa), 1e-12f);
  const float kp = 1.0f / fmaxf(sqrtf(sp), 1e-12f);
  int pa = __builtin_amdgcn_cvt_pk_fp8_f32(va.x * ka, va.y * ka, 0, false);
  pa     = __builtin_amdgcn_cvt_pk_fp8_f32(va.z * ka, va.w * ka, pa, true);
  int pp = __builtin_amdgcn_cvt_pk_fp8_f32(vp.x * kp, vp.y * kp, 0, false);
  pp     = __builtin_amdgcn_cvt_pk_fp8_f32(vp.z * kp, vp.w * kp, pp, true);
  ((int*)(a8 + (size_t)row * DD))[lane] = pa;
  ((int*)(p8 + (size_t)row * DD))[lane] = pp;
  // exact quantized dot for the diagonal (byte selector must be literal)
  float d = __builtin_amdgcn_cvt_f32_fp8(pa, 0) * __builtin_amdgcn_cvt_f32_fp8(pp, 0)
          + __builtin_amdgcn_cvt_f32_fp8(pa, 1) * __builtin_amdgcn_cvt_f32_fp8(pp, 1)
          + __builtin_amdgcn_cvt_f32_fp8(pa, 2) * __builtin_amdgcn_cvt_f32_fp8(pp, 2)
          + __builtin_amdgcn_cvt_f32_fp8(pa, 3) * __builtin_amdgcn_cvt_f32_fp8(pp, 3);
#pragma unroll
  for (int m = 32; m >= 1; m >>= 1) d += __shfl_xor(d, m, 64);
  if (lane == 0) diag[row] = d;
}

// Fragment read from swizzled LDS tile: slot (row, c) holds global granule
// c ^ (row&15); returns global bytes [ks*128+quad*32 .. +32) of `row`.
__device__ __forceinline__ int8v frag(const unsigned char* S, int row, int ks,
                                      int quad, int l16) {
  const int c0 = ks * 8 + quad * 2;
  const int4v lo = *(const int4v*)(S + row * DD + (((c0 + 0) ^ l16) << 4));
  const int4v hi = *(const int4v*)(S + row * DD + (((c0 + 1) ^ l16) << 4));
  return __builtin_shufflevector(lo, hi, 0, 1, 2, 3, 4, 5, 6, 7);
}

// 32 KB tile global->VGPR (coalesced 16B/lane) and VGPR->LDS (XOR swizzle)
__device__ __forceinline__ void loadp(uint4* pr, const unsigned char* gbase, int t) {
#pragma unroll
  for (int k = 0; k < 4; ++k)
    pr[k] = *(const uint4*)(gbase + (size_t)(k * 512 + t) * 16);
}
__device__ __forceinline__ void storep(unsigned char* lds, const uint4* pr, int t) {
#pragma unroll
  for (int k = 0; k < 4; ++k) {
    const int c = k * 512 + t;
    const int r = c >> 4, g = c & 15;
    *(uint4*)(lds + r * DD + (((g ^ (r & 15))) << 4)) = pr[k];
  }
}

// ------ kernel 2: register-prefetch double-buffered MX-fp8 GEMM + stats ----
// No global_load_lds anywhere (R9's DS-ops-concurrent-with-LDS-DMA NaN'd).
// Pipeline per tile: ds_write pregs->Bs[ct&1]; barrier; issue global prefetch
// of tile ct+1 into pregs (in flight across MFMA+epilogue+next ds_write);
// frag reads + 16 MFMAs + epilogue. One barrier per tile.
// LDS 98 KB -> 1 block/CU; no min-waves bound so regs are plentiful (no spill).
__global__ __launch_bounds__(512) void gemm_stats(
    const unsigned char* __restrict__ a8, const unsigned char* __restrict__ p8,
    float* __restrict__ rsum, float* __restrict__ rmax, int Btot) {
  __shared__ __align__(16) unsigned char As[BM * DD];      // 32 KB
  __shared__ __align__(16) unsigned char Bs[2][BM * DD];   // 2 x 32 KB
  __shared__ float red_sum[2][BM];
  __shared__ float red_max[2][BM];

  const int t = threadIdx.x;
  const int wave = t >> 6, lane = t & 63;
  const int wm = wave & 3, wn = wave >> 2;      // 4 row-groups x 2 col-groups
  const int quad = lane >> 4, l16 = lane & 15;
  const int row0    = blockIdx.y * BM;
  const int colbase = blockIdx.x * (NCT * BM);
  const bool hasdiag = ((int)(blockIdx.y >> 2) == (int)blockIdx.x);

  uint4 pr[4];
  // ---- stage A tile via regs, then load B tile 0 into regs ----
  loadp(pr, a8 + (size_t)row0 * DD, t);
  storep(As, pr, t);                               // waits A loads (dep-based)
  loadp(pr, p8 + (size_t)colbase * DD, t);         // B tile 0 -> regs
  __syncthreads();                                 // As visible; pr drained

  float se_run[2][4], mx_run[2][4];
#pragma unroll
  for (int a = 0; a < 2; ++a)
#pragma unroll
    for (int b = 0; b < 4; ++b) { se_run[a][b] = 0.f; mx_run[a][b] = -INFINITY; }

  for (int ct = 0; ct < NCT; ++ct) {
    // pr holds tile ct; buffer Bs[ct&1] was last read at ct-2 (drained at
    // barrier of ct-1) -> safe to overwrite.
    storep((unsigned char*)Bs[ct & 1], pr, t);
    __syncthreads();                               // tile ct visible
    if (ct + 1 < NCT)                              // prefetch tile ct+1; next
      loadp(pr, p8 + (size_t)(colbase + (ct + 1) * BM) * DD, t);  // drain is
                                                   // AFTER its consumption
    const unsigned char* Bh = Bs[ct & 1];
    floatx4 acc[2][4];
#pragma unroll
    for (int a = 0; a < 2; ++a)
#pragma unroll
      for (int b = 0; b < 4; ++b) acc[a][b] = (floatx4){0.f, 0.f, 0.f, 0.f};

#pragma unroll
    for (int ks = 0; ks < 2; ++ks) {
      const int8v af0 = frag(As, wm * 32 + l16,      ks, quad, l16);
      const int8v af1 = frag(As, wm * 32 + 16 + l16, ks, quad, l16);
#pragma unroll
      for (int ni = 0; ni < 4; ++ni) {
        const int8v bf = frag(Bh, wn * 64 + ni * 16 + l16, ks, quad, l16);
        acc[0][ni] = __builtin_amdgcn_mfma_scale_f32_16x16x128_f8f6f4(
            af0, bf, acc[0][ni], 0, 0, 0, SC1, 0, SC1);
        acc[1][ni] = __builtin_amdgcn_mfma_scale_f32_16x16x128_f8f6f4(
            af1, bf, acc[1][ni], 0, 0, 0, SC1, 0, SC1);
      }
    }

    // ---- fused stats epilogue (C/D: col=lane&15, row=quad*4+reg) ----
    const int col0 = colbase + ct * BM;
    if (!hasdiag) {
#pragma unroll
      for (int mi = 0; mi < 2; ++mi)
#pragma unroll
        for (int reg = 0; reg < 4; ++reg)
#pragma unroll
          for (int ni = 0; ni < 4; ++ni) {
            const float s = acc[mi][ni][reg];
            se_run[mi][reg] += __expf(s * TEMP_INV);
            mx_run[mi][reg] = fmaxf(mx_run[mi][reg], s);
          }
    } else {
#pragma unroll
      for (int mi = 0; mi < 2; ++mi)
#pragma unroll
        for (int reg = 0; reg < 4; ++reg) {
          const int i = row0 + wm * 32 + mi * 16 + quad * 4 + reg;
#pragma unroll
          for (int ni = 0; ni < 4; ++ni) {
            const float s = acc[mi][ni][reg];
            const int j = col0 + wn * 64 + ni * 16 + l16;
            se_run[mi][reg] += __expf(s * TEMP_INV);
            mx_run[mi][reg] = fmaxf(mx_run[mi][reg], (i == j) ? -INFINITY : s);
          }
        }
    }
  }

  // once-per-block 16-lane cross reduction
#pragma unroll
  for (int mi = 0; mi < 2; ++mi) {
#pragma unroll
    for (int reg = 0; reg < 4; ++reg) {
      float se = se_run[mi][reg], mx = mx_run[mi][reg];
#pragma unroll
      for (int m = 1; m < 16; m <<= 1) {
        se += __shfl_xor(se, m, 64);
        mx = fmaxf(mx, __shfl_xor(mx, m, 64));
      }
      if (l16 == 0) {
        const int rb = wm * 32 + mi * 16 + quad * 4 + reg;
        red_sum[wn][rb] = se;
        red_max[wn][rb] = mx;
      }
    }
  }
  __syncthreads();
  if (t < BM) {
    rsum[(size_t)blockIdx.x * Btot + row0 + t] = red_sum[0][t] + red_sum[1][t];
    rmax[(size_t)blockIdx.x * Btot + row0 + t] = fmaxf(red_max[0][t], red_max[1][t]);
  }
}

// ---- kernel 3: per-row loss from partials, block-reduce, atomic mean ----
__global__ __launch_bounds__(256) void row_loss_kernel(
    const float* __restrict__ rsum, const float* __restrict__ rmax,
    const float* __restrict__ diag, float* __restrict__ out, int Btot, int NG) {
  const int i = blockIdx.x * 256 + threadIdx.x;
  float s = 0.f, m = -INFINITY;
  for (int c = 0; c < NG; ++c) {
    s += rsum[(size_t)c * Btot + i];
    m = fmaxf(m, rmax[(size_t)c * Btot + i]);
  }
  float rl = __logf(s + __expf(m * TEMP_INV)) - diag[i] * TEMP_INV;
#pragma unroll
  for (int mm = 32; mm >= 1; mm >>= 1) rl += __shfl_xor(rl, mm, 64);
  __shared__ float red[4];
  if ((threadIdx.x & 63) == 0) red[threadIdx.x >> 6] = rl;
  __syncthreads();
  if (threadIdx.x == 0)
    atomicAdd(out, (red[0] + red[1] + red[2] + red[3]) / (float)Btot);
}

extern "C" void kernel_launch(void* const* d_in, const int* in_sizes, int n_in,
                              void* d_out, int out_size, void* d_ws, size_t ws_size,
                              hipStream_t stream) {
  const float* anchor   = (const float*)d_in[0];
  const float* positive = (const float*)d_in[1];
  const int B  = in_sizes[0] / DD;     // 8192
  const int NG = B / (BM * NCT);       // 16 column groups
  const size_t BD = (size_t)B * DD;

  // ws: a8(2MB) | p8(2MB) | rsum(NG*B) | rmax(NG*B) | diag(B)
  unsigned char* a8 = (unsigned char*)d_ws;
  unsigned char* p8 = a8 + BD;
  float* rsum  = (float*)(p8 + BD);
  float* rmax  = rsum + (size_t)NG * B;
  float* diag  = rmax + (size_t)NG * B;

  (void)hipMemsetAsync(d_out, 0, sizeof(float), stream);
  nrm_kernel<<<B / 4, 256, 0, stream>>>(anchor, positive, a8, p8, diag);
  dim3 g2(NG, B / BM);
  gemm_stats<<<g2, 512, 0, stream>>>(a8, p8, rsum, rmax, B);
  row_loss_kernel<<<B / 256, 256, 0, stream>>>(rsum, rmax, diag, (float*)d_out, B, NG);
}

// Round 12
// 99.463 us; speedup vs baseline: 1.2610x; 1.2610x over previous
//
#include <hip/hip_runtime.h>
#include <hip/hip_bf16.h>

using floatx4 = __attribute__((ext_vector_type(4))) float;
using int4v   = __attribute__((ext_vector_type(4))) int;
using int8v   = __attribute__((ext_vector_type(8))) int;

#define TEMP_INV 14.285714285714286f  // 1/0.07
#define DD 256   // feature dim; one fp8 row = 256 B
#define BM 128
#define NCT 8    // column tiles per block -> grid 8x64 = 512 = 2 blocks/CU exact
#define SC1 127  // e8m0 exponent 127 -> scale 1.0

typedef const __attribute__((address_space(1))) unsigned int* gptr_t;
typedef __attribute__((address_space(3))) unsigned int* lptr_t;

__device__ __forceinline__ void async_cp16(const void* g, void* l) {
  __builtin_amdgcn_global_load_lds((gptr_t)g, (lptr_t)l, 16, 0, 0);
}

// ---- kernel 1: L2 normalize rows -> fp8 e4m3, plus exact fp8 diag dot ----
__global__ __launch_bounds__(256) void nrm_kernel(
    const float* __restrict__ anchor, const float* __restrict__ positive,
    unsigned char* __restrict__ a8, unsigned char* __restrict__ p8,
    float* __restrict__ diag) {
  const int wave = threadIdx.x >> 6;
  const int lane = threadIdx.x & 63;
  const int row  = blockIdx.x * 4 + wave;
  const float4 va = ((const float4*)(anchor   + (size_t)row * DD))[lane];
  const float4 vp = ((const float4*)(positive + (size_t)row * DD))[lane];
  float sa = va.x * va.x + va.y * va.y + va.z * va.z + va.w * va.w;
  float sp = vp.x * vp.x + vp.y * vp.y + vp.z * vp.z + vp.w * vp.w;
#pragma unroll
  for (int m = 32; m >= 1; m >>= 1) {
    sa += __shfl_xor(sa, m, 64);
    sp += __shfl_xor(sp, m, 64);
  }
  const float ka = 1.0f / fmaxf(sqrtf(sa), 1e-12f);
  const float kp = 1.0f / fmaxf(sqrtf(sp), 1e-12f);
  int pa = __builtin_amdgcn_cvt_pk_fp8_f32(va.x * ka, va.y * ka, 0, false);
  pa     = __builtin_amdgcn_cvt_pk_fp8_f32(va.z * ka, va.w * ka, pa, true);
  int pp = __builtin_amdgcn_cvt_pk_fp8_f32(vp.x * kp, vp.y * kp, 0, false);
  pp     = __builtin_amdgcn_cvt_pk_fp8_f32(vp.z * kp, vp.w * kp, pp, true);
  ((int*)(a8 + (size_t)row * DD))[lane] = pa;
  ((int*)(p8 + (size_t)row * DD))[lane] = pp;
  // exact quantized dot for the diagonal (byte selector must be literal)
  float d = __builtin_amdgcn_cvt_f32_fp8(pa, 0) * __builtin_amdgcn_cvt_f32_fp8(pp, 0)
          + __builtin_amdgcn_cvt_f32_fp8(pa, 1) * __builtin_amdgcn_cvt_f32_fp8(pp, 1)
          + __builtin_amdgcn_cvt_f32_fp8(pa, 2) * __builtin_amdgcn_cvt_f32_fp8(pp, 2)
          + __builtin_amdgcn_cvt_f32_fp8(pa, 3) * __builtin_amdgcn_cvt_f32_fp8(pp, 3);
#pragma unroll
  for (int m = 32; m >= 1; m >>= 1) d += __shfl_xor(d, m, 64);
  if (lane == 0) diag[row] = d;
}

// Fragment read from swizzled LDS tile: slot (row, c) holds global granule
// c ^ (row&15); returns global bytes [ks*128+quad*32 .. +32) of `row`.
__device__ __forceinline__ int8v frag(const unsigned char* S, int row, int ks,
                                      int quad, int l16) {
  const int c0 = ks * 8 + quad * 2;
  const int4v lo = *(const int4v*)(S + row * DD + (((c0 + 0) ^ l16) << 4));
  const int4v hi = *(const int4v*)(S + row * DD + (((c0 + 1) ^ l16) << 4));
  return __builtin_shufflevector(lo, hi, 0, 1, 2, 3, 4, 5, 6, 7);
}

// ------ kernel 2: 512 threads / 8 waves, 32x64 frags per wave ------
// R8 structure (proven fastest): A tile staged once via global_load_lds,
// B tiles staged per-ct, transient frag reads, staging issued post-barrier
// and covered by the exp/max epilogue. NCT=8 -> 512 blocks = 2/CU exact.
__global__ __launch_bounds__(512, 4) void gemm_stats(
    const unsigned char* __restrict__ a8, const unsigned char* __restrict__ p8,
    float* __restrict__ rsum, float* __restrict__ rmax, int Btot) {
  __shared__ __align__(16) unsigned char As[BM * DD];  // 32 KB, lives all kernel
  __shared__ __align__(16) unsigned char Bs[BM * DD];  // 32 KB, per-ct
  __shared__ float red_sum[2][BM];
  __shared__ float red_max[2][BM];

  const int t = threadIdx.x;
  const int wave = t >> 6, lane = t & 63;
  const int wm = wave & 3, wn = wave >> 2;      // 4 row-groups x 2 col-groups
  const int quad = lane >> 4, l16 = lane & 15;
  const int row0    = blockIdx.y * BM;
  const int colbase = blockIdx.x * (NCT * BM);
  const bool hasdiag = ((int)(blockIdx.y >> 3) == (int)blockIdx.x);

  // staging decomposition: lane = r4*16 + cg
  const int r4 = lane >> 4;
  const int cg = lane & 15;

  // ---- stage A tile (once) and B tile for ct=0 ----
#pragma unroll
  for (int q = 0; q < 4; ++q) {
    const int rb = q * 32 + wave * 4;           // wave-uniform base row
    const int r  = rb + r4;
    async_cp16(a8 + (size_t)(row0 + r) * DD + (cg ^ (r & 15)) * 16,
               &As[rb * DD]);
  }
#pragma unroll
  for (int q = 0; q < 4; ++q) {
    const int rb = q * 32 + wave * 4;
    const int r  = rb + r4;
    async_cp16(p8 + (size_t)(colbase + r) * DD + (cg ^ (r & 15)) * 16,
               &Bs[rb * DD]);
  }

  float se_run[2][4], mx_run[2][4];
#pragma unroll
  for (int a = 0; a < 2; ++a)
#pragma unroll
    for (int b = 0; b < 4; ++b) { se_run[a][b] = 0.f; mx_run[a][b] = -INFINITY; }

  for (int ct = 0; ct < NCT; ++ct) {
    __syncthreads();  // As + Bs[ct] staged & visible

    floatx4 acc[2][4];
#pragma unroll
    for (int a = 0; a < 2; ++a)
#pragma unroll
      for (int b = 0; b < 4; ++b) acc[a][b] = (floatx4){0.f, 0.f, 0.f, 0.f};

#pragma unroll
    for (int ks = 0; ks < 2; ++ks) {
      const int8v af0 = frag(As, wm * 32 + l16,      ks, quad, l16);
      const int8v af1 = frag(As, wm * 32 + 16 + l16, ks, quad, l16);
#pragma unroll
      for (int ni = 0; ni < 4; ++ni) {
        const int8v bf = frag(Bs, wn * 64 + ni * 16 + l16, ks, quad, l16);
        acc[0][ni] = __builtin_amdgcn_mfma_scale_f32_16x16x128_f8f6f4(
            af0, bf, acc[0][ni], 0, 0, 0, SC1, 0, SC1);
        acc[1][ni] = __builtin_amdgcn_mfma_scale_f32_16x16x128_f8f6f4(
            af1, bf, acc[1][ni], 0, 0, 0, SC1, 0, SC1);
      }
    }

    __syncthreads();  // all waves done reading Bs
    if (ct + 1 < NCT) {  // issue next tile's staging; overlaps epilogue below
      const int colb = colbase + (ct + 1) * BM;
#pragma unroll
      for (int q = 0; q < 4; ++q) {
        const int rb = q * 32 + wave * 4;
        const int r  = rb + r4;
        async_cp16(p8 + (size_t)(colb + r) * DD + (cg ^ (r & 15)) * 16,
                   &Bs[rb * DD]);
      }
    }

    // ---- fused stats epilogue (C/D: col=lane&15, row=quad*4+reg) ----
    const int col0 = colbase + ct * BM;
    if (!hasdiag) {
#pragma unroll
      for (int mi = 0; mi < 2; ++mi)
#pragma unroll
        for (int reg = 0; reg < 4; ++reg)
#pragma unroll
          for (int ni = 0; ni < 4; ++ni) {
            const float s = acc[mi][ni][reg];
            se_run[mi][reg] += __expf(s * TEMP_INV);
            mx_run[mi][reg] = fmaxf(mx_run[mi][reg], s);
          }
    } else {
#pragma unroll
      for (int mi = 0; mi < 2; ++mi)
#pragma unroll
        for (int reg = 0; reg < 4; ++reg) {
          const int i = row0 + wm * 32 + mi * 16 + quad * 4 + reg;
#pragma unroll
          for (int ni = 0; ni < 4; ++ni) {
            const float s = acc[mi][ni][reg];
            const int j = col0 + wn * 64 + ni * 16 + l16;
            se_run[mi][reg] += __expf(s * TEMP_INV);
            mx_run[mi][reg] = fmaxf(mx_run[mi][reg], (i == j) ? -INFINITY : s);
          }
        }
    }
  }

  // once-per-block 16-lane cross reduction
#pragma unroll
  for (int mi = 0; mi < 2; ++mi) {
#pragma unroll
    for (int reg = 0; reg < 4; ++reg) {
      float se = se_run[mi][reg], mx = mx_run[mi][reg];
#pragma unroll
      for (int m = 1; m < 16; m <<= 1) {
        se += __shfl_xor(se, m, 64);
        mx = fmaxf(mx, __shfl_xor(mx, m, 64));
      }
      if (l16 == 0) {
        const int rb = wm * 32 + mi * 16 + quad * 4 + reg;
        red_sum[wn][rb] = se;
        red_max[wn][rb] = mx;
      }
    }
  }
  __syncthreads();
  if (t < BM) {
    rsum[(size_t)blockIdx.x * Btot + row0 + t] = red_sum[0][t] + red_sum[1][t];
    rmax[(size_t)blockIdx.x * Btot + row0 + t] = fmaxf(red_max[0][t], red_max[1][t]);
  }
}

// ---- kernel 3: per-row loss from partials, block-reduce, atomic mean ----
__global__ __launch_bounds__(256) void row_loss_kernel(
    const float* __restrict__ rsum, const float* __restrict__ rmax,
    const float* __restrict__ diag, float* __restrict__ out, int Btot, int NG) {
  const int i = blockIdx.x * 256 + threadIdx.x;
  float s = 0.f, m = -INFINITY;
  for (int c = 0; c < NG; ++c) {
    s += rsum[(size_t)c * Btot + i];
    m = fmaxf(m, rmax[(size_t)c * Btot + i]);
  }
  float rl = __logf(s + __expf(m * TEMP_INV)) - diag[i] * TEMP_INV;
#pragma unroll
  for (int mm = 32; mm >= 1; mm >>= 1) rl += __shfl_xor(rl, mm, 64);
  __shared__ float red[4];
  if ((threadIdx.x & 63) == 0) red[threadIdx.x >> 6] = rl;
  __syncthreads();
  if (threadIdx.x == 0)
    atomicAdd(out, (red[0] + red[1] + red[2] + red[3]) / (float)Btot);
}

extern "C" void kernel_launch(void* const* d_in, const int* in_sizes, int n_in,
                              void* d_out, int out_size, void* d_ws, size_t ws_size,
                              hipStream_t stream) {
  const float* anchor   = (const float*)d_in[0];
  const float* positive = (const float*)d_in[1];
  const int B  = in_sizes[0] / DD;     // 8192
  const int NG = B / (BM * NCT);       // 8 column groups
  const size_t BD = (size_t)B * DD;

  // ws: a8(2MB) | p8(2MB) | rsum(NG*B) | rmax(NG*B) | diag(B)
  unsigned char* a8 = (unsigned char*)d_ws;
  unsigned char* p8 = a8 + BD;
  float* rsum  = (float*)(p8 + BD);
  float* rmax  = rsum + (size_t)NG * B;
  float* diag  = rmax + (size_t)NG * B;

  (void)hipMemsetAsync(d_out, 0, sizeof(float), stream);
  nrm_kernel<<<B / 4, 256, 0, stream>>>(anchor, positive, a8, p8, diag);
  dim3 g2(NG, B / BM);
  gemm_stats<<<g2, 512, 0, stream>>>(a8, p8, rsum, rmax, B);
  row_loss_kernel<<<B / 256, 256, 0, stream>>>(rsum, rmax, diag, (float*)d_out, B, NG);
}

// Round 13
// 96.476 us; speedup vs baseline: 1.3001x; 1.0310x over previous
//
#include <hip/hip_runtime.h>
#include <hip/hip_bf16.h>

using floatx4 = __attribute__((ext_vector_type(4))) float;
using int4v   = __attribute__((ext_vector_type(4))) int;
using int8v   = __attribute__((ext_vector_type(8))) int;

#define TEMP_INV 14.285714285714286f  // 1/0.07
#define DD 256   // feature dim; one fp8 row = 256 B
#define BM 128
#define NCT 8    // column tiles per block -> grid 8x64 = 512 = 2 blocks/CU exact
#define SC1 127  // e8m0 exponent 127 -> scale 1.0

typedef const __attribute__((address_space(1))) unsigned int* gptr_t;
typedef __attribute__((address_space(3))) unsigned int* lptr_t;

__device__ __forceinline__ void async_cp16(const void* g, void* l) {
  __builtin_amdgcn_global_load_lds((gptr_t)g, (lptr_t)l, 16, 0, 0);
}

// ---- kernel 1: L2 normalize rows -> fp8 e4m3, exact fp8 diag dot, and ----
// ---- zero the output scalar (replaces a hipMemsetAsync dispatch).      ----
__global__ __launch_bounds__(256) void nrm_kernel(
    const float* __restrict__ anchor, const float* __restrict__ positive,
    unsigned char* __restrict__ a8, unsigned char* __restrict__ p8,
    float* __restrict__ diag, float* __restrict__ out) {
  if (blockIdx.x == 0 && threadIdx.x == 0) out[0] = 0.f;  // visible to later
                                                          // kernels (stream order)
  const int wave = threadIdx.x >> 6;
  const int lane = threadIdx.x & 63;
  const int row  = blockIdx.x * 4 + wave;
  const float4 va = ((const float4*)(anchor   + (size_t)row * DD))[lane];
  const float4 vp = ((const float4*)(positive + (size_t)row * DD))[lane];
  float sa = va.x * va.x + va.y * va.y + va.z * va.z + va.w * va.w;
  float sp = vp.x * vp.x + vp.y * vp.y + vp.z * vp.z + vp.w * vp.w;
#pragma unroll
  for (int m = 32; m >= 1; m >>= 1) {
    sa += __shfl_xor(sa, m, 64);
    sp += __shfl_xor(sp, m, 64);
  }
  const float ka = 1.0f / fmaxf(sqrtf(sa), 1e-12f);
  const float kp = 1.0f / fmaxf(sqrtf(sp), 1e-12f);
  int pa = __builtin_amdgcn_cvt_pk_fp8_f32(va.x * ka, va.y * ka, 0, false);
  pa     = __builtin_amdgcn_cvt_pk_fp8_f32(va.z * ka, va.w * ka, pa, true);
  int pp = __builtin_amdgcn_cvt_pk_fp8_f32(vp.x * kp, vp.y * kp, 0, false);
  pp     = __builtin_amdgcn_cvt_pk_fp8_f32(vp.z * kp, vp.w * kp, pp, true);
  ((int*)(a8 + (size_t)row * DD))[lane] = pa;
  ((int*)(p8 + (size_t)row * DD))[lane] = pp;
  // exact quantized dot for the diagonal (byte selector must be literal)
  float d = __builtin_amdgcn_cvt_f32_fp8(pa, 0) * __builtin_amdgcn_cvt_f32_fp8(pp, 0)
          + __builtin_amdgcn_cvt_f32_fp8(pa, 1) * __builtin_amdgcn_cvt_f32_fp8(pp, 1)
          + __builtin_amdgcn_cvt_f32_fp8(pa, 2) * __builtin_amdgcn_cvt_f32_fp8(pp, 2)
          + __builtin_amdgcn_cvt_f32_fp8(pa, 3) * __builtin_amdgcn_cvt_f32_fp8(pp, 3);
#pragma unroll
  for (int m = 32; m >= 1; m >>= 1) d += __shfl_xor(d, m, 64);
  if (lane == 0) diag[row] = d;
}

// Fragment read from swizzled LDS tile: slot (row, c) holds global granule
// c ^ (row&15); returns global bytes [ks*128+quad*32 .. +32) of `row`.
__device__ __forceinline__ int8v frag(const unsigned char* S, int row, int ks,
                                      int quad, int l16) {
  const int c0 = ks * 8 + quad * 2;
  const int4v lo = *(const int4v*)(S + row * DD + (((c0 + 0) ^ l16) << 4));
  const int4v hi = *(const int4v*)(S + row * DD + (((c0 + 1) ^ l16) << 4));
  return __builtin_shufflevector(lo, hi, 0, 1, 2, 3, 4, 5, 6, 7);
}

// ------ kernel 2: 512 threads / 8 waves, 32x64 frags per wave ------
// R8/R11 structure (proven fastest): A tile staged once via global_load_lds,
// B tiles staged per-ct, transient frag reads, staging issued post-barrier
// and covered by the exp/max epilogue. NCT=8 -> 512 blocks = 2/CU exact.
__global__ __launch_bounds__(512, 4) void gemm_stats(
    const unsigned char* __restrict__ a8, const unsigned char* __restrict__ p8,
    float* __restrict__ rsum, float* __restrict__ rmax, int Btot) {
  __shared__ __align__(16) unsigned char As[BM * DD];  // 32 KB, lives all kernel
  __shared__ __align__(16) unsigned char Bs[BM * DD];  // 32 KB, per-ct
  __shared__ float red_sum[2][BM];
  __shared__ float red_max[2][BM];

  const int t = threadIdx.x;
  const int wave = t >> 6, lane = t & 63;
  const int wm = wave & 3, wn = wave >> 2;      // 4 row-groups x 2 col-groups
  const int quad = lane >> 4, l16 = lane & 15;
  const int row0    = blockIdx.y * BM;
  const int colbase = blockIdx.x * (NCT * BM);
  const bool hasdiag = ((int)(blockIdx.y >> 3) == (int)blockIdx.x);

  // staging decomposition: lane = r4*16 + cg
  const int r4 = lane >> 4;
  const int cg = lane & 15;

  // ---- stage A tile (once) and B tile for ct=0 ----
#pragma unroll
  for (int q = 0; q < 4; ++q) {
    const int rb = q * 32 + wave * 4;           // wave-uniform base row
    const int r  = rb + r4;
    async_cp16(a8 + (size_t)(row0 + r) * DD + (cg ^ (r & 15)) * 16,
               &As[rb * DD]);
  }
#pragma unroll
  for (int q = 0; q < 4; ++q) {
    const int rb = q * 32 + wave * 4;
    const int r  = rb + r4;
    async_cp16(p8 + (size_t)(colbase + r) * DD + (cg ^ (r & 15)) * 16,
               &Bs[rb * DD]);
  }

  float se_run[2][4], mx_run[2][4];
#pragma unroll
  for (int a = 0; a < 2; ++a)
#pragma unroll
    for (int b = 0; b < 4; ++b) { se_run[a][b] = 0.f; mx_run[a][b] = -INFINITY; }

  for (int ct = 0; ct < NCT; ++ct) {
    __syncthreads();  // As + Bs[ct] staged & visible

    floatx4 acc[2][4];
#pragma unroll
    for (int a = 0; a < 2; ++a)
#pragma unroll
      for (int b = 0; b < 4; ++b) acc[a][b] = (floatx4){0.f, 0.f, 0.f, 0.f};

#pragma unroll
    for (int ks = 0; ks < 2; ++ks) {
      const int8v af0 = frag(As, wm * 32 + l16,      ks, quad, l16);
      const int8v af1 = frag(As, wm * 32 + 16 + l16, ks, quad, l16);
#pragma unroll
      for (int ni = 0; ni < 4; ++ni) {
        const int8v bf = frag(Bs, wn * 64 + ni * 16 + l16, ks, quad, l16);
        acc[0][ni] = __builtin_amdgcn_mfma_scale_f32_16x16x128_f8f6f4(
            af0, bf, acc[0][ni], 0, 0, 0, SC1, 0, SC1);
        acc[1][ni] = __builtin_amdgcn_mfma_scale_f32_16x16x128_f8f6f4(
            af1, bf, acc[1][ni], 0, 0, 0, SC1, 0, SC1);
      }
    }

    __syncthreads();  // all waves done reading Bs
    if (ct + 1 < NCT) {  // issue next tile's staging; overlaps epilogue below
      const int colb = colbase + (ct + 1) * BM;
#pragma unroll
      for (int q = 0; q < 4; ++q) {
        const int rb = q * 32 + wave * 4;
        const int r  = rb + r4;
        async_cp16(p8 + (size_t)(colb + r) * DD + (cg ^ (r & 15)) * 16,
                   &Bs[rb * DD]);
      }
    }

    // ---- fused stats epilogue (C/D: col=lane&15, row=quad*4+reg) ----
    const int col0 = colbase + ct * BM;
    if (!hasdiag) {
#pragma unroll
      for (int mi = 0; mi < 2; ++mi)
#pragma unroll
        for (int reg = 0; reg < 4; ++reg)
#pragma unroll
          for (int ni = 0; ni < 4; ++ni) {
            const float s = acc[mi][ni][reg];
            se_run[mi][reg] += __expf(s * TEMP_INV);
            mx_run[mi][reg] = fmaxf(mx_run[mi][reg], s);
          }
    } else {
#pragma unroll
      for (int mi = 0; mi < 2; ++mi)
#pragma unroll
        for (int reg = 0; reg < 4; ++reg) {
          const int i = row0 + wm * 32 + mi * 16 + quad * 4 + reg;
#pragma unroll
          for (int ni = 0; ni < 4; ++ni) {
            const float s = acc[mi][ni][reg];
            const int j = col0 + wn * 64 + ni * 16 + l16;
            se_run[mi][reg] += __expf(s * TEMP_INV);
            mx_run[mi][reg] = fmaxf(mx_run[mi][reg], (i == j) ? -INFINITY : s);
          }
        }
    }
  }

  // once-per-block 16-lane cross reduction
#pragma unroll
  for (int mi = 0; mi < 2; ++mi) {
#pragma unroll
    for (int reg = 0; reg < 4; ++reg) {
      float se = se_run[mi][reg], mx = mx_run[mi][reg];
#pragma unroll
      for (int m = 1; m < 16; m <<= 1) {
        se += __shfl_xor(se, m, 64);
        mx = fmaxf(mx, __shfl_xor(mx, m, 64));
      }
      if (l16 == 0) {
        const int rb = wm * 32 + mi * 16 + quad * 4 + reg;
        red_sum[wn][rb] = se;
        red_max[wn][rb] = mx;
      }
    }
  }
  __syncthreads();
  if (t < BM) {
    rsum[(size_t)blockIdx.x * Btot + row0 + t] = red_sum[0][t] + red_sum[1][t];
    rmax[(size_t)blockIdx.x * Btot + row0 + t] = fmaxf(red_max[0][t], red_max[1][t]);
  }
}

// ---- kernel 3: per-row loss from partials, block-reduce, atomic mean ----
__global__ __launch_bounds__(256) void row_loss_kernel(
    const float* __restrict__ rsum, const float* __restrict__ rmax,
    const float* __restrict__ diag, float* __restrict__ out, int Btot, int NG) {
  const int i = blockIdx.x * 256 + threadIdx.x;
  float s = 0.f, m = -INFINITY;
  for (int c = 0; c < NG; ++c) {
    s += rsum[(size_t)c * Btot + i];
    m = fmaxf(m, rmax[(size_t)c * Btot + i]);
  }
  float rl = __logf(s + __expf(m * TEMP_INV)) - diag[i] * TEMP_INV;
#pragma unroll
  for (int mm = 32; mm >= 1; mm >>= 1) rl += __shfl_xor(rl, mm, 64);
  __shared__ float red[4];
  if ((threadIdx.x & 63) == 0) red[threadIdx.x >> 6] = rl;
  __syncthreads();
  if (threadIdx.x == 0)
    atomicAdd(out, (red[0] + red[1] + red[2] + red[3]) / (float)Btot);
}

extern "C" void kernel_launch(void* const* d_in, const int* in_sizes, int n_in,
                              void* d_out, int out_size, void* d_ws, size_t ws_size,
                              hipStream_t stream) {
  const float* anchor   = (const float*)d_in[0];
  const float* positive = (const float*)d_in[1];
  const int B  = in_sizes[0] / DD;     // 8192
  const int NG = B / (BM * NCT);       // 8 column groups
  const size_t BD = (size_t)B * DD;

  // ws: a8(2MB) | p8(2MB) | rsum(NG*B) | rmax(NG*B) | diag(B)
  unsigned char* a8 = (unsigned char*)d_ws;
  unsigned char* p8 = a8 + BD;
  float* rsum  = (float*)(p8 + BD);
  float* rmax  = rsum + (size_t)NG * B;
  float* diag  = rmax + (size_t)NG * B;

  nrm_kernel<<<B / 4, 256, 0, stream>>>(anchor, positive, a8, p8, diag,
                                        (float*)d_out);
  dim3 g2(NG, B / BM);
  gemm_stats<<<g2, 512, 0, stream>>>(a8, p8, rsum, rmax, B);
  row_loss_kernel<<<B / 256, 256, 0, stream>>>(rsum, rmax, diag, (float*)d_out, B, NG);
}